// Round 1
// baseline (4224.903 us; speedup 1.0000x reference)
//
#include <hip/hip_runtime.h>
#include <hip/hip_bf16.h>
#include <stdint.h>

typedef __bf16 bf16_t;
typedef __bf16 bf16x8 __attribute__((ext_vector_type(8)));
typedef __bf16 bf16x4_t __attribute__((ext_vector_type(4)));
typedef float f32x4 __attribute__((ext_vector_type(4)));

#define T_STEPS 512
#define B_SZ 64
#define I_SZ 512
#define H_SZ 512
#define G4 2048         // 4*H
#define NB 4            // batch groups
#define BS 16           // batch rows per group
#define NC 32           // column groups per batch group
#define CS 16           // h cols per WG
#define KT 32           // K tiles of 32 (K = 1024)
#define A_STRIDE 1032   // LDS row stride in elems (1024 + 8 pad -> 2-way-free banks)

// ws layout (bytes)
#define XBF_OFF   0ull
#define WBF_OFF   33554432ull                    // 512*64*512*2
#define BALL_OFF  (WBF_OFF + 4194304ull)         // 2048*1024*2
#define HEX_OFF   (BALL_OFF + 8192ull)           // 2048*4
#define CNT_OFF   (HEX_OFF + 131072ull)          // 2*64*512*2

__device__ __forceinline__ float sigmoid_fast(float x) {
  return 1.f / (1.f + __expf(-x));
}
__device__ __forceinline__ float tanh_fast(float x) {
  float xc = fminf(fmaxf(x, -10.f), 10.f);
  float e = __expf(2.f * xc);
  return (e - 1.f) / (e + 1.f);
}

// ---------- prep: cast x to bf16 ----------
__global__ void prep_x(const float* __restrict__ x, bf16_t* __restrict__ xbf) {
  const int n4 = (T_STEPS * B_SZ * I_SZ) / 4;
  int i = blockIdx.x * blockDim.x + threadIdx.x;
  int stride = gridDim.x * blockDim.x;
  for (; i < n4; i += stride) {
    float4 v = ((const float4*)x)[i];
    bf16x4_t o = { (bf16_t)v.x, (bf16_t)v.y, (bf16_t)v.z, (bf16_t)v.w };
    ((bf16x4_t*)xbf)[i] = o;
  }
}

// ---------- prep: W_all bf16, b_all f32, zero h-exchange + counters ----------
__global__ void prep_rest(const float* __restrict__ wf, const float* __restrict__ wi,
                          const float* __restrict__ wg, const float* __restrict__ wo,
                          const float* __restrict__ bfv, const float* __restrict__ biv,
                          const float* __restrict__ bgv, const float* __restrict__ bov,
                          bf16_t* __restrict__ wbf, float* __restrict__ ball,
                          uint32_t* __restrict__ hexz, int* __restrict__ cnt) {
  int gtid = blockIdx.x * blockDim.x + threadIdx.x;
  int stride = gridDim.x * blockDim.x;
  const int WCH = (G4 * 1024) / 4;  // 524288 float4 chunks
  for (int i = gtid; i < WCH; i += stride) {
    int r = i >> 8;               // W_all row (0..2047)
    int c = (i & 255) << 2;       // col base
    int g = r >> 9, sr = r & 511;
    const float* src = (g == 0) ? wf : (g == 1) ? wi : (g == 2) ? wg : wo;
    float4 v = *(const float4*)(src + (size_t)sr * 1024 + c);
    bf16x4_t o = { (bf16_t)v.x, (bf16_t)v.y, (bf16_t)v.z, (bf16_t)v.w };
    *(bf16x4_t*)(wbf + (size_t)r * 1024 + c) = o;
  }
  for (int i = gtid; i < G4; i += stride) {
    int g = i >> 9;
    const float* src = (g == 0) ? bfv : (g == 1) ? biv : (g == 2) ? bgv : bov;
    ball[i] = src[i & 511];
  }
  for (int i = gtid; i < (2 * B_SZ * H_SZ * 2) / 4; i += stride) hexz[i] = 0;
  for (int i = gtid; i < NB * T_STEPS; i += stride) cnt[i] = 0;
}

// ---------- main recurrent kernel: 128 WGs, batch-group-local sync ----------
__global__ __launch_bounds__(256, 1) void qlstm_main(
    const bf16_t* __restrict__ xbf, const bf16_t* __restrict__ wbf,
    const float* __restrict__ ball, bf16_t* __restrict__ hexch,
    int* __restrict__ cnt, float* __restrict__ out) {
  const int wg = blockIdx.x;
  const int bg = wg >> 5;      // batch group 0..3
  const int ic = wg & 31;      // column group 0..31
  const int tid = threadIdx.x;
  const int wave = tid >> 6;   // 0..3 == gate index (N-tile)
  const int lane = tid & 63;
  const int l15 = lane & 15;
  const int quad = lane >> 4;

  __shared__ __align__(16) bf16_t As[BS * A_STRIDE];   // [16 rows][1024+pad] combined A
  __shared__ float Gs[BS][4][CS + 1];                  // gate pre-activations

  // Register-resident B fragments: W_all row = gate*512 + ic*16 + (lane&15),
  // k = kt*32 + quad*8 .. +8  (B[k][n] = W_all[n][k])
  bf16x8 wfr[KT];
  {
    const bf16_t* wp = wbf + ((size_t)(wave * 512 + ic * CS + l15)) * 1024 + quad * 8;
#pragma unroll
    for (int kt = 0; kt < KT; ++kt)
      wfr[kt] = *(const bf16x8*)(wp + kt * 32);
  }

  // elementwise mapping: thread -> (batch row, h col) of this WG's 16x16 slice
  const int erow = tid >> 4;
  const int ecol = tid & 15;
  const float bias_f = ball[0 * 512 + ic * CS + ecol];
  const float bias_i = ball[1 * 512 + ic * CS + ecol];
  const float bias_g = ball[2 * 512 + ic * CS + ecol];
  const float bias_o = ball[3 * 512 + ic * CS + ecol];

  float c_state = 0.f;
  int* mycnt = cnt + bg * T_STEPS;
  const size_t out_hx = (size_t)T_STEPS * B_SZ * H_SZ;
  const int brow = bg * BS + erow;
  const int hcol = ic * CS + ecol;

#pragma unroll 1
  for (int t = 0; t < T_STEPS; ++t) {
    if (t > 0) {
      if (tid == 0) {
        while (__hip_atomic_load(&mycnt[t - 1], __ATOMIC_RELAXED,
                                 __HIP_MEMORY_SCOPE_AGENT) < NC)
          __builtin_amdgcn_s_sleep(2);
      }
      __syncthreads();
      __builtin_amdgcn_fence(__ATOMIC_ACQUIRE, "agent");  // inv L1/L2 before h read
    }

    // stage A = [x_t | h_{t-1}] (16 x 1024 bf16) into LDS, 16B chunks
    {
      const bf16_t* xs = xbf + ((size_t)t * B_SZ + bg * BS) * I_SZ;
      const bf16_t* hs = hexch + (size_t)((((t & 1) ^ 1)) * B_SZ + bg * BS) * H_SZ;
#pragma unroll
      for (int q = 0; q < 4; ++q) {
        int chunk = q * 256 + tid;  // 0..1023
        int r = chunk >> 6, cc = chunk & 63;
        *(uint4*)&As[r * A_STRIDE + cc * 8] = *(const uint4*)&xs[r * I_SZ + cc * 8];
        *(uint4*)&As[r * A_STRIDE + 512 + cc * 8] = *(const uint4*)&hs[r * H_SZ + cc * 8];
      }
    }
    __syncthreads();

    // GEMM: one gate (16x16 C tile) per wave, K=1024, 4 independent acc chains
    f32x4 a0 = {0, 0, 0, 0}, a1 = {0, 0, 0, 0}, a2 = {0, 0, 0, 0}, a3 = {0, 0, 0, 0};
    const bf16_t* ap = &As[l15 * A_STRIDE + quad * 8];
#pragma unroll
    for (int kt = 0; kt < KT; kt += 4) {
      bf16x8 f0 = *(const bf16x8*)(ap + (kt + 0) * 32);
      bf16x8 f1 = *(const bf16x8*)(ap + (kt + 1) * 32);
      bf16x8 f2 = *(const bf16x8*)(ap + (kt + 2) * 32);
      bf16x8 f3 = *(const bf16x8*)(ap + (kt + 3) * 32);
      a0 = __builtin_amdgcn_mfma_f32_16x16x32_bf16(f0, wfr[kt + 0], a0, 0, 0, 0);
      a1 = __builtin_amdgcn_mfma_f32_16x16x32_bf16(f1, wfr[kt + 1], a1, 0, 0, 0);
      a2 = __builtin_amdgcn_mfma_f32_16x16x32_bf16(f2, wfr[kt + 2], a2, 0, 0, 0);
      a3 = __builtin_amdgcn_mfma_f32_16x16x32_bf16(f3, wfr[kt + 3], a3, 0, 0, 0);
    }
    f32x4 acc = (a0 + a1) + (a2 + a3);
    // C/D layout: col = lane&15, row = quad*4 + i  [m89]
#pragma unroll
    for (int i = 0; i < 4; ++i) Gs[quad * 4 + i][wave][l15] = acc[i];
    __syncthreads();

    // LSTM cell (fp32), per-thread c state
    float fg = sigmoid_fast(Gs[erow][0][ecol] + bias_f);
    float ig = sigmoid_fast(Gs[erow][1][ecol] + bias_i);
    float gg = tanh_fast(Gs[erow][2][ecol] + bias_g);
    float og = sigmoid_fast(Gs[erow][3][ecol] + bias_o);
    c_state = fg * c_state + ig * gg;
    float h = og * tanh_fast(c_state);

    out[((size_t)t * B_SZ + brow) * H_SZ + hcol] = h;
    hexch[(size_t)((t & 1) * B_SZ + brow) * H_SZ + hcol] = (bf16_t)h;
    if (t == T_STEPS - 1) {
      out[out_hx + (size_t)brow * H_SZ + hcol] = h;
      out[out_hx + (size_t)(B_SZ * H_SZ) + (size_t)brow * H_SZ + hcol] = c_state;
    }

    __syncthreads();  // drains vmcnt(0): all WG stores complete before publish
    if (tid == 0)
      __hip_atomic_fetch_add(&mycnt[t], 1, __ATOMIC_RELEASE, __HIP_MEMORY_SCOPE_AGENT);
  }
}

extern "C" void kernel_launch(void* const* d_in, const int* in_sizes, int n_in,
                              void* d_out, int out_size, void* d_ws, size_t ws_size,
                              hipStream_t stream) {
  const float* x   = (const float*)d_in[0];
  const float* Wf  = (const float*)d_in[1];
  const float* bfv = (const float*)d_in[2];
  const float* Wi  = (const float*)d_in[3];
  const float* biv = (const float*)d_in[4];
  const float* Wg  = (const float*)d_in[5];
  const float* bgv = (const float*)d_in[6];
  const float* Wo  = (const float*)d_in[7];
  const float* bov = (const float*)d_in[8];
  float* out = (float*)d_out;

  char* ws = (char*)d_ws;
  bf16_t* xbf   = (bf16_t*)(ws + XBF_OFF);
  bf16_t* wbf   = (bf16_t*)(ws + WBF_OFF);
  float*  ball  = (float*)(ws + BALL_OFF);
  bf16_t* hexch = (bf16_t*)(ws + HEX_OFF);
  int*    cnt   = (int*)(ws + CNT_OFF);

  prep_x<<<dim3(2048), dim3(256), 0, stream>>>(x, xbf);
  prep_rest<<<dim3(1024), dim3(256), 0, stream>>>(Wf, Wi, Wg, Wo, bfv, biv, bgv, bov,
                                                  wbf, ball, (uint32_t*)hexch, cnt);
  qlstm_main<<<dim3(NB * NC), dim3(256), 0, stream>>>(xbf, wbf, ball, hexch, cnt, out);
}

// Round 2
// 1981.138 us; speedup vs baseline: 2.1326x; 2.1326x over previous
//
#include <hip/hip_runtime.h>
#include <hip/hip_bf16.h>
#include <stdint.h>

typedef __bf16 bf16_t;
typedef __bf16 bf16x8 __attribute__((ext_vector_type(8)));
typedef __bf16 bf16x4_t __attribute__((ext_vector_type(4)));
typedef float f32x4 __attribute__((ext_vector_type(4)));

#define T_STEPS 512
#define B_SZ 64
#define I_SZ 512
#define H_SZ 512
#define G4 2048         // 4*H
#define NB 4            // batch groups
#define BS 16           // batch rows per group
#define NC 32           // column groups per batch group
#define CS 16           // h cols per WG
#define KT 32           // K tiles of 32 (K = 1024)
#define A_STRIDE 1032   // LDS row stride elems: 516 dwords ≡ 4 (mod 32) -> 2-way free

// ws layout (bytes)
#define XBF_OFF   0ull
#define WBF_OFF   33554432ull                    // 512*64*512*2
#define BALL_OFF  (WBF_OFF + 4194304ull)         // 2048*1024*2
#define HEX_OFF   (BALL_OFF + 8192ull)           // 2048*4
#define CNT_OFF   (HEX_OFF + 131072ull)          // 2*64*512*2

__device__ __forceinline__ float sigmoid_fast(float x) {
  return 1.f / (1.f + __expf(-x));
}
__device__ __forceinline__ float tanh_fast(float x) {
  float xc = fminf(fmaxf(x, -10.f), 10.f);
  float e = __expf(2.f * xc);
  return (e - 1.f) / (e + 1.f);
}

// ---- device-coherent (L1+L2 bypass -> Infinity Cache) accessors ----
__device__ __forceinline__ uint4 load_b128_cc(const void* addr) {
  uint4 v;
  asm volatile("global_load_dwordx4 %0, %1, off sc0 sc1"
               : "=v"(v) : "v"(addr) : "memory");
  return v;
}
__device__ __forceinline__ void store_b16_cc(void* addr, uint32_t v) {
  asm volatile("global_store_short %0, %1, off sc0 sc1"
               :: "v"(addr), "v"(v) : "memory");
}
__device__ __forceinline__ void wait_vm0() {
  asm volatile("s_waitcnt vmcnt(0)" ::: "memory");
}

// ---------- prep: cast x to bf16 ----------
__global__ void prep_x(const float* __restrict__ x, bf16_t* __restrict__ xbf) {
  const int n4 = (T_STEPS * B_SZ * I_SZ) / 4;
  int i = blockIdx.x * blockDim.x + threadIdx.x;
  int stride = gridDim.x * blockDim.x;
  for (; i < n4; i += stride) {
    float4 v = ((const float4*)x)[i];
    bf16x4_t o = { (bf16_t)v.x, (bf16_t)v.y, (bf16_t)v.z, (bf16_t)v.w };
    ((bf16x4_t*)xbf)[i] = o;
  }
}

// ---------- prep: W_all bf16, b_all f32, zero h-exchange + counters ----------
__global__ void prep_rest(const float* __restrict__ wf, const float* __restrict__ wi,
                          const float* __restrict__ wg, const float* __restrict__ wo,
                          const float* __restrict__ bfv, const float* __restrict__ biv,
                          const float* __restrict__ bgv, const float* __restrict__ bov,
                          bf16_t* __restrict__ wbf, float* __restrict__ ball,
                          uint32_t* __restrict__ hexz, int* __restrict__ cnt) {
  int gtid = blockIdx.x * blockDim.x + threadIdx.x;
  int stride = gridDim.x * blockDim.x;
  const int WCH = (G4 * 1024) / 4;  // 524288 float4 chunks
  for (int i = gtid; i < WCH; i += stride) {
    int r = i >> 8;               // W_all row (0..2047)
    int c = (i & 255) << 2;       // col base
    int g = r >> 9, sr = r & 511;
    const float* src = (g == 0) ? wf : (g == 1) ? wi : (g == 2) ? wg : wo;
    float4 v = *(const float4*)(src + (size_t)sr * 1024 + c);
    bf16x4_t o = { (bf16_t)v.x, (bf16_t)v.y, (bf16_t)v.z, (bf16_t)v.w };
    *(bf16x4_t*)(wbf + (size_t)r * 1024 + c) = o;
  }
  for (int i = gtid; i < G4; i += stride) {
    int g = i >> 9;
    const float* src = (g == 0) ? bfv : (g == 1) ? biv : (g == 2) ? bgv : bov;
    ball[i] = src[i & 511];
  }
  for (int i = gtid; i < (2 * B_SZ * H_SZ * 2) / 4; i += stride) hexz[i] = 0;
  for (int i = gtid; i < NB * T_STEPS; i += stride) cnt[i] = 0;
}

// ---------- main recurrent kernel: 128 WGs, batch-group-local sync ----------
__global__ __launch_bounds__(256, 1) void qlstm_main(
    const bf16_t* __restrict__ xbf, const bf16_t* __restrict__ wbf,
    const float* __restrict__ ball, bf16_t* __restrict__ hexch,
    int* __restrict__ cnt, float* __restrict__ out) {
  const int wg = blockIdx.x;
  const int bg = wg >> 5;      // batch group 0..3
  const int ic = wg & 31;      // column group 0..31
  const int tid = threadIdx.x;
  const int wave = tid >> 6;   // 0..3 == gate index (N-tile)
  const int lane = tid & 63;
  const int l15 = lane & 15;
  const int quad = lane >> 4;

  __shared__ __align__(16) bf16_t As[BS * A_STRIDE];   // [16 rows][1024+pad]
  __shared__ float Gs[BS][4][CS + 2];                  // pad+2: 2-way banks (free)

  // Register-resident B fragments: W_all row = gate*512 + ic*16 + (lane&15),
  // k = kt*32 + quad*8 .. +8  (B[k][n] = W_all[n][k])
  bf16x8 wfr[KT];
  {
    const bf16_t* wp = wbf + ((size_t)(wave * 512 + ic * CS + l15)) * 1024 + quad * 8;
#pragma unroll
    for (int kt = 0; kt < KT; ++kt)
      wfr[kt] = *(const bf16x8*)(wp + kt * 32);
  }

  // elementwise mapping: thread -> (batch row, h col) of this WG's 16x16 slice
  const int erow = tid >> 4;
  const int ecol = tid & 15;
  const float bias_f = ball[0 * 512 + ic * CS + ecol];
  const float bias_i = ball[1 * 512 + ic * CS + ecol];
  const float bias_g = ball[2 * 512 + ic * CS + ecol];
  const float bias_o = ball[3 * 512 + ic * CS + ecol];

  float c_state = 0.f;
  float h = 0.f;
  int* mycnt = cnt + bg * T_STEPS;
  const size_t out_hx = (size_t)T_STEPS * B_SZ * H_SZ;
  const int brow = bg * BS + erow;
  const int hcol = ic * CS + ecol;

  // staging geometry (16B chunks): per thread 4 chunks of x, 4 of h
  int srow[4], scol[4];
#pragma unroll
  for (int q = 0; q < 4; ++q) {
    int chunk = q * 256 + tid;          // 0..1023
    srow[q] = chunk >> 6;               // 0..15
    scol[q] = (chunk & 63) * 8;         // bf16 col base, step 8 (16B)
  }

#pragma unroll 1
  for (int t = 0; t < T_STEPS; ++t) {
    // issue x loads early (normal cached) — they complete under the poll
    uint4 xr[4];
    {
      const bf16_t* xs = xbf + ((size_t)t * B_SZ + bg * BS) * I_SZ;
#pragma unroll
      for (int q = 0; q < 4; ++q)
        xr[q] = *(const uint4*)&xs[srow[q] * I_SZ + scol[q]];
    }

    if (t > 0) {
      if (tid == 0) {
        while (__hip_atomic_load(&mycnt[t - 1], __ATOMIC_RELAXED,
                                 __HIP_MEMORY_SCOPE_AGENT) < NC)
          __builtin_amdgcn_s_sleep(1);
      }
      __syncthreads();
    }

    // h slice via coherent bypass loads (Infinity Cache)
    uint4 hr[4];
    {
      const bf16_t* hs = hexch + (size_t)(((t & 1) ^ 1) * B_SZ + bg * BS) * H_SZ;
#pragma unroll
      for (int q = 0; q < 4; ++q)
        hr[q] = load_b128_cc(&hs[srow[q] * H_SZ + scol[q]]);
    }

    // x half to LDS (compiler waits xr's vmcnt)
#pragma unroll
    for (int q = 0; q < 4; ++q)
      *(uint4*)&As[srow[q] * A_STRIDE + scol[q]] = xr[q];
    wait_vm0();  // drain bypass h loads (also covers stray out-stores)
#pragma unroll
    for (int q = 0; q < 4; ++q)
      *(uint4*)&As[srow[q] * A_STRIDE + 512 + scol[q]] = hr[q];
    __syncthreads();

    // GEMM: one gate (16x16 C tile) per wave, K=1024, 4 independent acc chains
    f32x4 a0 = {0, 0, 0, 0}, a1 = {0, 0, 0, 0}, a2 = {0, 0, 0, 0}, a3 = {0, 0, 0, 0};
    const bf16_t* ap = &As[l15 * A_STRIDE + quad * 8];
#pragma unroll
    for (int kt = 0; kt < KT; kt += 4) {
      bf16x8 f0 = *(const bf16x8*)(ap + (kt + 0) * 32);
      bf16x8 f1 = *(const bf16x8*)(ap + (kt + 1) * 32);
      bf16x8 f2 = *(const bf16x8*)(ap + (kt + 2) * 32);
      bf16x8 f3 = *(const bf16x8*)(ap + (kt + 3) * 32);
      a0 = __builtin_amdgcn_mfma_f32_16x16x32_bf16(f0, wfr[kt + 0], a0, 0, 0, 0);
      a1 = __builtin_amdgcn_mfma_f32_16x16x32_bf16(f1, wfr[kt + 1], a1, 0, 0, 0);
      a2 = __builtin_amdgcn_mfma_f32_16x16x32_bf16(f2, wfr[kt + 2], a2, 0, 0, 0);
      a3 = __builtin_amdgcn_mfma_f32_16x16x32_bf16(f3, wfr[kt + 3], a3, 0, 0, 0);
    }
    f32x4 acc = (a0 + a1) + (a2 + a3);
    // C/D layout: col = lane&15, row = quad*4 + i  [m89]
#pragma unroll
    for (int i = 0; i < 4; ++i) Gs[quad * 4 + i][wave][l15] = acc[i];
    __syncthreads();

    // LSTM cell (fp32), per-thread c state
    float fg = sigmoid_fast(Gs[erow][0][ecol] + bias_f);
    float ig = sigmoid_fast(Gs[erow][1][ecol] + bias_i);
    float gg = tanh_fast(Gs[erow][2][ecol] + bias_g);
    float og = sigmoid_fast(Gs[erow][3][ecol] + bias_o);
    c_state = fg * c_state + ig * gg;
    h = og * tanh_fast(c_state);

    // publish h FIRST (critical path), out stores after the signal
    union { bf16_t b; unsigned short u; } cvt;
    cvt.b = (bf16_t)h;
    store_b16_cc(&hexch[(size_t)((t & 1) * B_SZ + brow) * H_SZ + hcol],
                 (uint32_t)cvt.u);
    wait_vm0();          // my h store is at the coherence point
    __syncthreads();     // whole WG's h stores drained
    if (tid == 0)
      __hip_atomic_fetch_add(&mycnt[t], 1, __ATOMIC_RELAXED,
                             __HIP_MEMORY_SCOPE_AGENT);

    out[((size_t)t * B_SZ + brow) * H_SZ + hcol] = h;
  }

  out[out_hx + (size_t)brow * H_SZ + hcol] = h;
  out[out_hx + (size_t)(B_SZ * H_SZ) + (size_t)brow * H_SZ + hcol] = c_state;
}

extern "C" void kernel_launch(void* const* d_in, const int* in_sizes, int n_in,
                              void* d_out, int out_size, void* d_ws, size_t ws_size,
                              hipStream_t stream) {
  const float* x   = (const float*)d_in[0];
  const float* Wf  = (const float*)d_in[1];
  const float* bfv = (const float*)d_in[2];
  const float* Wi  = (const float*)d_in[3];
  const float* biv = (const float*)d_in[4];
  const float* Wg  = (const float*)d_in[5];
  const float* bgv = (const float*)d_in[6];
  const float* Wo  = (const float*)d_in[7];
  const float* bov = (const float*)d_in[8];
  float* out = (float*)d_out;

  char* ws = (char*)d_ws;
  bf16_t* xbf   = (bf16_t*)(ws + XBF_OFF);
  bf16_t* wbf   = (bf16_t*)(ws + WBF_OFF);
  float*  ball  = (float*)(ws + BALL_OFF);
  bf16_t* hexch = (bf16_t*)(ws + HEX_OFF);
  int*    cnt   = (int*)(ws + CNT_OFF);

  prep_x<<<dim3(2048), dim3(256), 0, stream>>>(x, xbf);
  prep_rest<<<dim3(1024), dim3(256), 0, stream>>>(Wf, Wi, Wg, Wo, bfv, biv, bgv, bov,
                                                  wbf, ball, (uint32_t*)hexch, cnt);
  qlstm_main<<<dim3(NB * NC), dim3(256), 0, stream>>>(xbf, wbf, ball, hexch, cnt, out);
}